// Round 1
// baseline (3513.308 us; speedup 1.0000x reference)
//
#include <hip/hip_runtime.h>

#define NU 100000
#define NI 200000
#define NN 300000
#define NNZE 1200000
#define D 64
#define OS 256   // (L+1)*D output row stride

// ---------------- concat user_emb/item_emb -> out chunk0 ----------------
__global__ void k_concat(const float* __restrict__ ue, const float* __restrict__ ie,
                         float* __restrict__ out) {
    int idx = blockIdx.x * blockDim.x + threadIdx.x;
    if (idx >= NN * 16) return;
    int n = idx >> 4, c = idx & 15;
    float4 v;
    if (n < NU) v = ((const float4*)(ue + (size_t)n * D))[c];
    else        v = ((const float4*)(ie + (size_t)(n - NU) * D))[c];
    ((float4*)(out + (size_t)n * OS))[c] = v;
}

// ---------------- SpMM: side[rows[e]] += vals[e] * emb[cols[e]] ----------------
// emb points at out + l*64 (row stride OS). 16 lanes per edge, float4 each.
__global__ void k_spmm(const int* __restrict__ rows, const int* __restrict__ cols,
                       const float* __restrict__ vals, const float* __restrict__ emb,
                       float* __restrict__ side) {
    int t = blockIdx.x * blockDim.x + threadIdx.x;
    int e = t >> 4, lane = t & 15;
    if (e >= NNZE) return;
    int r = rows[e], c = cols[e];
    float v = vals[e];
    float4 g = *(const float4*)(emb + (size_t)c * OS + lane * 4);
    float* dst = side + (size_t)r * D + lane * 4;
    atomicAdd(dst + 0, v * g.x);
    atomicAdd(dst + 1, v * g.y);
    atomicAdd(dst + 2, v * g.z);
    atomicAdd(dst + 3, v * g.w);
}

// ---------------- dense: outN = leakyrelu(side@Wc + bc + (side*emb)@We + be) ----
// 64 nodes per block, 256 threads, per-thread tile = 2 nodes x 8 output cols.
__global__ __launch_bounds__(256, 2) void k_dense(
    const float* __restrict__ side, const float* __restrict__ embL,
    const float* __restrict__ Wc, const float* __restrict__ bc,
    const float* __restrict__ We, const float* __restrict__ be,
    float* __restrict__ outN) {
    __shared__ float sW[2][64][64];  // [Wc|We][k][j]  32KB
    __shared__ float sS[64][64];     // side transposed [k][n] 16KB
    __shared__ float sE[64][64];     // emb  transposed [k][n] 16KB

    int tid = threadIdx.x;
    int n0 = blockIdx.x * 64;

    // stage weights (contiguous float4)
    {
        int base = tid * 16;
        #pragma unroll
        for (int i = 0; i < 4; i++) {
            *(float4*)(&sW[0][0][0] + base + i * 4) = *(const float4*)(Wc + base + i * 4);
            *(float4*)(&sW[1][0][0] + base + i * 4) = *(const float4*)(We + base + i * 4);
        }
    }
    // stage side/emb transposed: thread loads float4 over k, scatters to [k][n]
    {
        int n = tid & 63, kc = tid >> 6;
        bool ok = (n0 + n) < NN;
        #pragma unroll
        for (int it = 0; it < 4; it++) {
            int k0 = kc * 4 + it * 16;
            float4 s  = ok ? *(const float4*)(side + (size_t)(n0 + n) * D + k0)
                           : make_float4(0.f, 0.f, 0.f, 0.f);
            float4 em = ok ? *(const float4*)(embL + (size_t)(n0 + n) * OS + k0)
                           : make_float4(0.f, 0.f, 0.f, 0.f);
            sS[k0 + 0][n] = s.x;  sS[k0 + 1][n] = s.y;
            sS[k0 + 2][n] = s.z;  sS[k0 + 3][n] = s.w;
            sE[k0 + 0][n] = em.x; sE[k0 + 1][n] = em.y;
            sE[k0 + 2][n] = em.z; sE[k0 + 3][n] = em.w;
        }
    }
    __syncthreads();

    int b = tid & 7, a = tid >> 3;  // a in 0..31 -> nodes a*2, a*2+1 ; b -> cols b*8..b*8+7
    int j0 = b * 8;

    float acc[2][8];
    #pragma unroll
    for (int j = 0; j < 8; j++) {
        float bias = bc[j0 + j] + be[j0 + j];
        acc[0][j] = bias;
        acc[1][j] = bias;
    }

    #pragma unroll 8
    for (int k = 0; k < 64; k++) {
        float2 s  = *(float2*)&sS[k][a * 2];
        float2 em = *(float2*)&sE[k][a * 2];
        float t0 = s.x * em.x, t1 = s.y * em.y;
        float wcv[8], wev[8];
        *(float4*)&wcv[0] = *(float4*)&sW[0][k][j0];
        *(float4*)&wcv[4] = *(float4*)&sW[0][k][j0 + 4];
        *(float4*)&wev[0] = *(float4*)&sW[1][k][j0];
        *(float4*)&wev[4] = *(float4*)&sW[1][k][j0 + 4];
        #pragma unroll
        for (int j = 0; j < 8; j++) {
            acc[0][j] += s.x * wcv[j] + t0 * wev[j];
            acc[1][j] += s.y * wcv[j] + t1 * wev[j];
        }
    }

    #pragma unroll
    for (int i = 0; i < 2; i++) {
        int n = n0 + a * 2 + i;
        if (n < NN) {
            float o[8];
            #pragma unroll
            for (int j = 0; j < 8; j++) {
                float x = acc[i][j];
                o[j] = (x > 0.f) ? x : 0.2f * x;
            }
            *(float4*)(outN + (size_t)n * OS + j0)     = *(float4*)&o[0];
            *(float4*)(outN + (size_t)n * OS + j0 + 4) = *(float4*)&o[4];
        }
    }
}

// ---------------- in-place row-normalize of chunks 1..3 ----------------
__global__ void k_norm(float* __restrict__ out) {
    int t = blockIdx.x * blockDim.x + threadIdx.x;
    int rc = t >> 4, lane = t & 15;
    if (rc >= NN * 3) return;
    int r = rc / 3, c = rc % 3;
    float* p = out + (size_t)r * OS + (c + 1) * D + lane * 4;
    float4 v = *(float4*)p;
    float ss = v.x * v.x + v.y * v.y + v.z * v.z + v.w * v.w;
    ss += __shfl_xor(ss, 1);
    ss += __shfl_xor(ss, 2);
    ss += __shfl_xor(ss, 4);
    ss += __shfl_xor(ss, 8);
    float nrm = sqrtf(ss);
    float s = 1.0f / fmaxf(nrm, 1e-12f);
    v.x *= s; v.y *= s; v.z *= s; v.w *= s;
    *(float4*)p = v;
}

extern "C" void kernel_launch(void* const* d_in, const int* in_sizes, int n_in,
                              void* d_out, int out_size, void* d_ws, size_t ws_size,
                              hipStream_t stream) {
    const int*   rows = (const int*)d_in[0];
    const int*   cols = (const int*)d_in[1];
    const float* vals = (const float*)d_in[2];
    const float* ue   = (const float*)d_in[3];
    const float* ie   = (const float*)d_in[4];
    const float* Wc   = (const float*)d_in[5];
    const float* bc   = (const float*)d_in[6];
    const float* We   = (const float*)d_in[7];
    const float* be   = (const float*)d_in[8];
    float* out  = (float*)d_out;
    float* side = (float*)d_ws;  // NN*64 floats = 76.8 MB

    k_concat<<<(NN * 16 + 255) / 256, 256, 0, stream>>>(ue, ie, out);

    for (int l = 0; l < 3; l++) {
        hipMemsetAsync(side, 0, (size_t)NN * D * sizeof(float), stream);
        k_spmm<<<(NNZE * 16 + 255) / 256, 256, 0, stream>>>(
            rows, cols, vals, out + l * 64, side);
        k_dense<<<(NN + 63) / 64, 256, 0, stream>>>(
            side, out + l * 64, Wc + l * 4096, bc + l * 64,
            We + l * 4096, be + l * 64, out + (l + 1) * 64);
    }

    k_norm<<<(NN * 3 * 16 + 255) / 256, 256, 0, stream>>>(out);
}

// Round 2
// 886.558 us; speedup vs baseline: 3.9629x; 3.9629x over previous
//
#include <hip/hip_runtime.h>

#define NU 100000
#define NI 200000
#define NN 300000
#define NNZE 1200000
#define D 64
#define OS 256   // (L+1)*D output row stride

// ---------------- concat user_emb/item_emb -> out chunk0 ----------------
__global__ void k_concat(const float* __restrict__ ue, const float* __restrict__ ie,
                         float* __restrict__ out) {
    int idx = blockIdx.x * blockDim.x + threadIdx.x;
    if (idx >= NN * 16) return;
    int n = idx >> 4, c = idx & 15;
    float4 v;
    if (n < NU) v = ((const float4*)(ue + (size_t)n * D))[c];
    else        v = ((const float4*)(ie + (size_t)(n - NU) * D))[c];
    ((float4*)(out + (size_t)n * OS))[c] = v;
}

// ---------------- CSR build ----------------
__global__ void k_hist(const int* __restrict__ rows, int* __restrict__ cnt) {
    int e = blockIdx.x * blockDim.x + threadIdx.x;
    if (e < NNZE) atomicAdd(&cnt[rows[e]], 1);
}

// inclusive scan of cnt within 1024-blocks; rowptr[g+1]=partial, bsum[bid]=total
__global__ void k_scan1(const int* __restrict__ cnt, int* __restrict__ rowptr,
                        int* __restrict__ bsum) {
    __shared__ int s[1024];
    int t = threadIdx.x, g = blockIdx.x * 1024 + t;
    int x = (g < NN) ? cnt[g] : 0;
    s[t] = x;
    __syncthreads();
    for (int off = 1; off < 1024; off <<= 1) {
        int y = (t >= off) ? s[t - off] : 0;
        __syncthreads();
        s[t] += y;
        __syncthreads();
    }
    if (g < NN) rowptr[g + 1] = s[t];
    if (t == 1023) bsum[blockIdx.x] = s[1023];
}

__global__ void k_scan2(int* __restrict__ bsum, int nb) {
    __shared__ int s[512];
    int t = threadIdx.x;
    int x = (t < nb) ? bsum[t] : 0;
    s[t] = x;
    __syncthreads();
    for (int off = 1; off < 512; off <<= 1) {
        int y = (t >= off) ? s[t - off] : 0;
        __syncthreads();
        s[t] += y;
        __syncthreads();
    }
    if (t < nb) bsum[t] = s[t];
}

__global__ void k_scan3(int* __restrict__ rowptr, const int* __restrict__ bsum,
                        int* __restrict__ cur) {
    int t = threadIdx.x, g = blockIdx.x * 1024 + t;
    if (g < NN) {
        int off = (blockIdx.x > 0) ? bsum[blockIdx.x - 1] : 0;
        int v = rowptr[g + 1] + off;
        rowptr[g + 1] = v;
    }
    if (g == 0) rowptr[0] = 0;
}

__global__ void k_initcur(const int* __restrict__ rowptr, int* __restrict__ cur) {
    int g = blockIdx.x * blockDim.x + threadIdx.x;
    if (g < NN) cur[g] = rowptr[g];
}

__global__ void k_scatter(const int* __restrict__ rows, const int* __restrict__ cols,
                          const float* __restrict__ vals, int* __restrict__ cur,
                          int* __restrict__ cols_s, float* __restrict__ vals_s) {
    int e = blockIdx.x * blockDim.x + threadIdx.x;
    if (e >= NNZE) return;
    int r = rows[e];
    int pos = atomicAdd(&cur[r], 1);
    cols_s[pos] = cols[e];
    vals_s[pos] = vals[e];
}

// ---------------- fused layer: SpMM (CSR, in-LDS) + dense + leakyrelu ----------
// 64 nodes per block, 256 threads.
__global__ __launch_bounds__(256, 2) void k_layer(
    const int* __restrict__ rowptr, const int* __restrict__ cols_s,
    const float* __restrict__ vals_s,
    const float* __restrict__ embL,   // out + l*64, row stride OS
    const float* __restrict__ Wc, const float* __restrict__ bc,
    const float* __restrict__ We, const float* __restrict__ be,
    float* __restrict__ outN) {       // out + (l+1)*64, row stride OS
    __shared__ float sW[2][64][64];  // 32KB
    __shared__ float sS[64][64];     // side transposed [k][n] 16KB
    __shared__ float sE[64][64];     // emb  transposed [k][n] 16KB

    int tid = threadIdx.x;
    int n0 = blockIdx.x * 64;

    // stage weights
    {
        int base = tid * 16;
        #pragma unroll
        for (int i = 0; i < 4; i++) {
            *(float4*)(&sW[0][0][0] + base + i * 4) = *(const float4*)(Wc + base + i * 4);
            *(float4*)(&sW[1][0][0] + base + i * 4) = *(const float4*)(We + base + i * 4);
        }
    }
    // stage emb tile transposed
    {
        int n = tid & 63, kc = tid >> 6;
        bool ok = (n0 + n) < NN;
        #pragma unroll
        for (int it = 0; it < 4; it++) {
            int k0 = kc * 4 + it * 16;
            float4 em = ok ? *(const float4*)(embL + (size_t)(n0 + n) * OS + k0)
                           : make_float4(0.f, 0.f, 0.f, 0.f);
            sE[k0 + 0][n] = em.x; sE[k0 + 1][n] = em.y;
            sE[k0 + 2][n] = em.z; sE[k0 + 3][n] = em.w;
        }
    }
    // SpMM into sS: 16 lanes per row, 16 rows per pass, 4 passes
    {
        int lane = tid & 15, rsub = tid >> 4;
        #pragma unroll
        for (int pass = 0; pass < 4; pass++) {
            int n = pass * 16 + rsub;
            float4 acc = make_float4(0.f, 0.f, 0.f, 0.f);
            int r = n0 + n;
            if (r < NN) {
                int beg = rowptr[r], end = rowptr[r + 1];
                int i = beg;
                for (; i + 1 < end; i += 2) {
                    int c0 = cols_s[i], c1 = cols_s[i + 1];
                    float v0 = vals_s[i], v1 = vals_s[i + 1];
                    float4 g0 = *(const float4*)(embL + (size_t)c0 * OS + lane * 4);
                    float4 g1 = *(const float4*)(embL + (size_t)c1 * OS + lane * 4);
                    acc.x += v0 * g0.x + v1 * g1.x;
                    acc.y += v0 * g0.y + v1 * g1.y;
                    acc.z += v0 * g0.z + v1 * g1.z;
                    acc.w += v0 * g0.w + v1 * g1.w;
                }
                if (i < end) {
                    int c0 = cols_s[i];
                    float v0 = vals_s[i];
                    float4 g0 = *(const float4*)(embL + (size_t)c0 * OS + lane * 4);
                    acc.x += v0 * g0.x; acc.y += v0 * g0.y;
                    acc.z += v0 * g0.z; acc.w += v0 * g0.w;
                }
            }
            int k0 = lane * 4;
            sS[k0 + 0][n] = acc.x;
            sS[k0 + 1][n] = acc.y;
            sS[k0 + 2][n] = acc.z;
            sS[k0 + 3][n] = acc.w;
        }
    }
    __syncthreads();

    // dense: per-thread 2 nodes x 8 cols
    int b = tid & 7, a = tid >> 3;
    int j0 = b * 8;

    float acc[2][8];
    #pragma unroll
    for (int j = 0; j < 8; j++) {
        float bias = bc[j0 + j] + be[j0 + j];
        acc[0][j] = bias;
        acc[1][j] = bias;
    }

    #pragma unroll 8
    for (int k = 0; k < 64; k++) {
        float2 s  = *(float2*)&sS[k][a * 2];
        float2 em = *(float2*)&sE[k][a * 2];
        float t0 = s.x * em.x, t1 = s.y * em.y;
        float wcv[8], wev[8];
        *(float4*)&wcv[0] = *(float4*)&sW[0][k][j0];
        *(float4*)&wcv[4] = *(float4*)&sW[0][k][j0 + 4];
        *(float4*)&wev[0] = *(float4*)&sW[1][k][j0];
        *(float4*)&wev[4] = *(float4*)&sW[1][k][j0 + 4];
        #pragma unroll
        for (int j = 0; j < 8; j++) {
            acc[0][j] += s.x * wcv[j] + t0 * wev[j];
            acc[1][j] += s.y * wcv[j] + t1 * wev[j];
        }
    }

    #pragma unroll
    for (int i = 0; i < 2; i++) {
        int n = n0 + a * 2 + i;
        if (n < NN) {
            float o[8];
            #pragma unroll
            for (int j = 0; j < 8; j++) {
                float x = acc[i][j];
                o[j] = (x > 0.f) ? x : 0.2f * x;
            }
            *(float4*)(outN + (size_t)n * OS + j0)     = *(float4*)&o[0];
            *(float4*)(outN + (size_t)n * OS + j0 + 4) = *(float4*)&o[4];
        }
    }
}

// ---------------- in-place row-normalize of chunks 1..3 ----------------
__global__ void k_norm(float* __restrict__ out) {
    int t = blockIdx.x * blockDim.x + threadIdx.x;
    int rc = t >> 4, lane = t & 15;
    if (rc >= NN * 3) return;
    int r = rc / 3, c = rc % 3;
    float* p = out + (size_t)r * OS + (c + 1) * D + lane * 4;
    float4 v = *(float4*)p;
    float ss = v.x * v.x + v.y * v.y + v.z * v.z + v.w * v.w;
    ss += __shfl_xor(ss, 1);
    ss += __shfl_xor(ss, 2);
    ss += __shfl_xor(ss, 4);
    ss += __shfl_xor(ss, 8);
    float nrm = sqrtf(ss);
    float s = 1.0f / fmaxf(nrm, 1e-12f);
    v.x *= s; v.y *= s; v.z *= s; v.w *= s;
    *(float4*)p = v;
}

extern "C" void kernel_launch(void* const* d_in, const int* in_sizes, int n_in,
                              void* d_out, int out_size, void* d_ws, size_t ws_size,
                              hipStream_t stream) {
    const int*   rows = (const int*)d_in[0];
    const int*   cols = (const int*)d_in[1];
    const float* vals = (const float*)d_in[2];
    const float* ue   = (const float*)d_in[3];
    const float* ie   = (const float*)d_in[4];
    const float* Wc   = (const float*)d_in[5];
    const float* bc   = (const float*)d_in[6];
    const float* We   = (const float*)d_in[7];
    const float* be   = (const float*)d_in[8];
    float* out = (float*)d_out;

    // ws layout (ints/floats, 4B each): ~13.2 MB total
    int*   cnt    = (int*)d_ws;            // NN
    int*   rowptr = cnt + NN;              // NN+1
    int*   bsum   = rowptr + NN + 1;       // 512
    int*   cur    = bsum + 512;            // NN
    int*   cols_s = cur + NN;              // NNZE
    float* vals_s = (float*)(cols_s + NNZE);

    const int NB_SCAN = (NN + 1023) / 1024;  // 293

    // ---- build CSR ----
    hipMemsetAsync(cnt, 0, (size_t)NN * sizeof(int), stream);
    k_hist<<<(NNZE + 255) / 256, 256, 0, stream>>>(rows, cnt);
    k_scan1<<<NB_SCAN, 1024, 0, stream>>>(cnt, rowptr, bsum);
    k_scan2<<<1, 512, 0, stream>>>(bsum, NB_SCAN);
    k_scan3<<<NB_SCAN, 1024, 0, stream>>>(rowptr, bsum, cur);
    k_initcur<<<(NN + 255) / 256, 256, 0, stream>>>(rowptr, cur);
    k_scatter<<<(NNZE + 255) / 256, 256, 0, stream>>>(rows, cols, vals, cur,
                                                      cols_s, vals_s);

    // ---- embeddings ----
    k_concat<<<(NN * 16 + 255) / 256, 256, 0, stream>>>(ue, ie, out);

    for (int l = 0; l < 3; l++) {
        k_layer<<<(NN + 63) / 64, 256, 0, stream>>>(
            rowptr, cols_s, vals_s, out + l * 64,
            Wc + l * 4096, bc + l * 64, We + l * 4096, be + l * 64,
            out + (l + 1) * 64);
    }

    k_norm<<<(NN * 3 * 16 + 255) / 256, 256, 0, stream>>>(out);
}

// Round 4
// 681.590 us; speedup vs baseline: 5.1546x; 1.3007x over previous
//
#include <hip/hip_runtime.h>

#define NU 100000
#define NI 200000
#define NN 300000
#define NNZE 1200000
#define D 64
#define OS 256   // (L+1)*D output row stride

// ---------------- concat user_emb/item_emb -> out chunk0 ----------------
__global__ void k_concat(const float* __restrict__ ue, const float* __restrict__ ie,
                         float* __restrict__ out) {
    int idx = blockIdx.x * blockDim.x + threadIdx.x;
    if (idx >= NN * 16) return;
    int n = idx >> 4, c = idx & 15;
    float4 v;
    if (n < NU) v = ((const float4*)(ue + (size_t)n * D))[c];
    else        v = ((const float4*)(ie + (size_t)(n - NU) * D))[c];
    ((float4*)(out + (size_t)n * OS))[c] = v;
}

// ---------------- CSR build ----------------
__global__ void k_hist(const int* __restrict__ rows, int* __restrict__ cnt) {
    int e = blockIdx.x * blockDim.x + threadIdx.x;
    if (e < NNZE) atomicAdd(&cnt[rows[e]], 1);
}

__global__ void k_scan1(const int* __restrict__ cnt, int* __restrict__ rowptr,
                        int* __restrict__ bsum) {
    __shared__ int s[1024];
    int t = threadIdx.x, g = blockIdx.x * 1024 + t;
    int x = (g < NN) ? cnt[g] : 0;
    s[t] = x;
    __syncthreads();
    for (int off = 1; off < 1024; off <<= 1) {
        int y = (t >= off) ? s[t - off] : 0;
        __syncthreads();
        s[t] += y;
        __syncthreads();
    }
    if (g < NN) rowptr[g + 1] = s[t];
    if (t == 1023) bsum[blockIdx.x] = s[1023];
}

__global__ void k_scan2(int* __restrict__ bsum, int nb) {
    __shared__ int s[512];
    int t = threadIdx.x;
    int x = (t < nb) ? bsum[t] : 0;
    s[t] = x;
    __syncthreads();
    for (int off = 1; off < 512; off <<= 1) {
        int y = (t >= off) ? s[t - off] : 0;
        __syncthreads();
        s[t] += y;
        __syncthreads();
    }
    if (t < nb) bsum[t] = s[t];
}

// also initializes cur[] (folded k_initcur)
__global__ void k_scan3(int* __restrict__ rowptr, const int* __restrict__ bsum,
                        int* __restrict__ cur) {
    int t = threadIdx.x, g = blockIdx.x * 1024 + t;
    if (g < NN) {
        int off = (blockIdx.x > 0) ? bsum[blockIdx.x - 1] : 0;
        int v = rowptr[g + 1] + off;
        rowptr[g + 1] = v;
        if (g + 1 < NN) cur[g + 1] = v;
    }
    if (g == 0) { rowptr[0] = 0; cur[0] = 0; }
}

__global__ void k_scatter(const int* __restrict__ rows, const int* __restrict__ cols,
                          const float* __restrict__ vals, int* __restrict__ cur,
                          int* __restrict__ cols_s, float* __restrict__ vals_s) {
    int e = blockIdx.x * blockDim.x + threadIdx.x;
    if (e >= NNZE) return;
    int r = rows[e];
    int pos = atomicAdd(&cur[r], 1);
    cols_s[pos] = cols[e];
    vals_s[pos] = vals[e];
}

// ---------------- standalone CSR SpMM: side[g] = sum val*(norm?)*emb[c] -------
// emb rows hold NORMALIZED values for l>=1; scaling by norms[c] reconstructs
// the unnormalized activation. 16 lanes per row, float4 per lane.
template<bool SCALED>
__global__ __launch_bounds__(256) void k_spmm(
    const int* __restrict__ rowptr, const int* __restrict__ cols_s,
    const float* __restrict__ vals_s, const float* __restrict__ norms,
    const float* __restrict__ emb, float* __restrict__ side) {
    int t = blockIdx.x * blockDim.x + threadIdx.x;
    int g = t >> 4, lane = t & 15;
    if (g >= NN) return;
    int beg = rowptr[g], end = rowptr[g + 1];
    float ax = 0.f, ay = 0.f, az = 0.f, aw = 0.f;
    int i = beg;
    for (; i + 1 < end; i += 2) {
        int c0 = cols_s[i], c1 = cols_s[i + 1];
        float v0 = vals_s[i], v1 = vals_s[i + 1];
        if (SCALED) { v0 *= norms[c0]; v1 *= norms[c1]; }
        float4 g0 = *(const float4*)(emb + (size_t)c0 * OS + lane * 4);
        float4 g1 = *(const float4*)(emb + (size_t)c1 * OS + lane * 4);
        ax += v0 * g0.x + v1 * g1.x;
        ay += v0 * g0.y + v1 * g1.y;
        az += v0 * g0.z + v1 * g1.z;
        aw += v0 * g0.w + v1 * g1.w;
    }
    if (i < end) {
        int c0 = cols_s[i];
        float v0 = vals_s[i];
        if (SCALED) v0 *= norms[c0];
        float4 g0 = *(const float4*)(emb + (size_t)c0 * OS + lane * 4);
        ax += v0 * g0.x; ay += v0 * g0.y; az += v0 * g0.z; aw += v0 * g0.w;
    }
    *(float4*)(side + (size_t)g * D + lane * 4) = make_float4(ax, ay, az, aw);
}

// ---------------- dense + leakyrelu + L2-normalize (fused) --------------------
// embL holds normalized rows for l>=1 (SCALED=true): reconstruct unnormalized
// ew-operand by scaling row n with prev_norms[n] at staging time.
// Writes NORMALIZED rows to outN and the (new) norm to norms[].
template<bool SCALED>
__global__ __launch_bounds__(256, 2) void k_dense(
    const float* __restrict__ side, const float* __restrict__ embL,
    const float* __restrict__ Wc, const float* __restrict__ bc,
    const float* __restrict__ We, const float* __restrict__ be,
    float* __restrict__ outN, float* __restrict__ norms) {
    __shared__ float sW[2][64][64];  // 32KB
    __shared__ float sS[64][64];     // side transposed [k][n] 16KB
    __shared__ float sE[64][64];     // emb  transposed [k][n] 16KB

    int tid = threadIdx.x;
    int n0 = blockIdx.x * 64;

    {
        int base = tid * 16;
        #pragma unroll
        for (int i = 0; i < 4; i++) {
            *(float4*)(&sW[0][0][0] + base + i * 4) = *(const float4*)(Wc + base + i * 4);
            *(float4*)(&sW[1][0][0] + base + i * 4) = *(const float4*)(We + base + i * 4);
        }
    }
    {
        int n = tid & 63, kc = tid >> 6;
        bool ok = (n0 + n) < NN;
        float esc = 1.f;
        if (SCALED && ok) esc = norms[n0 + n];   // read BEFORE this block overwrites
        #pragma unroll
        for (int it = 0; it < 4; it++) {
            int k0 = kc * 4 + it * 16;
            float4 s  = ok ? *(const float4*)(side + (size_t)(n0 + n) * D + k0)
                           : make_float4(0.f, 0.f, 0.f, 0.f);
            float4 em = ok ? *(const float4*)(embL + (size_t)(n0 + n) * OS + k0)
                           : make_float4(0.f, 0.f, 0.f, 0.f);
            sS[k0 + 0][n] = s.x;  sS[k0 + 1][n] = s.y;
            sS[k0 + 2][n] = s.z;  sS[k0 + 3][n] = s.w;
            sE[k0 + 0][n] = em.x * esc; sE[k0 + 1][n] = em.y * esc;
            sE[k0 + 2][n] = em.z * esc; sE[k0 + 3][n] = em.w * esc;
        }
    }
    __syncthreads();

    int b = tid & 7, a = tid >> 3;
    int j0 = b * 8;

    float acc[2][8];
    #pragma unroll
    for (int j = 0; j < 8; j++) {
        float bias = bc[j0 + j] + be[j0 + j];
        acc[0][j] = bias;
        acc[1][j] = bias;
    }

    #pragma unroll 8
    for (int k = 0; k < 64; k++) {
        float2 s  = *(float2*)&sS[k][a * 2];
        float2 em = *(float2*)&sE[k][a * 2];
        float t0 = s.x * em.x, t1 = s.y * em.y;
        float wcv[8], wev[8];
        *(float4*)&wcv[0] = *(float4*)&sW[0][k][j0];
        *(float4*)&wcv[4] = *(float4*)&sW[0][k][j0 + 4];
        *(float4*)&wev[0] = *(float4*)&sW[1][k][j0];
        *(float4*)&wev[4] = *(float4*)&sW[1][k][j0 + 4];
        #pragma unroll
        for (int j = 0; j < 8; j++) {
            acc[0][j] += s.x * wcv[j] + t0 * wev[j];
            acc[1][j] += s.y * wcv[j] + t1 * wev[j];
        }
    }

    // leaky-relu + row ssq
    float o[2][8];
    float ssq[2];
    #pragma unroll
    for (int i = 0; i < 2; i++) {
        ssq[i] = 0.f;
        #pragma unroll
        for (int j = 0; j < 8; j++) {
            float x = acc[i][j];
            float y = (x > 0.f) ? x : 0.2f * x;
            o[i][j] = y;
            ssq[i] += y * y;
        }
    }
    #pragma unroll
    for (int i = 0; i < 2; i++) {
        ssq[i] += __shfl_xor(ssq[i], 1);
        ssq[i] += __shfl_xor(ssq[i], 2);
        ssq[i] += __shfl_xor(ssq[i], 4);
    }

    #pragma unroll
    for (int i = 0; i < 2; i++) {
        int n = n0 + a * 2 + i;
        if (n < NN) {
            float nrm = sqrtf(ssq[i]);
            float sc = 1.0f / fmaxf(nrm, 1e-12f);
            float4 lo = make_float4(o[i][0] * sc, o[i][1] * sc, o[i][2] * sc, o[i][3] * sc);
            float4 hi = make_float4(o[i][4] * sc, o[i][5] * sc, o[i][6] * sc, o[i][7] * sc);
            *(float4*)(outN + (size_t)n * OS + j0)     = lo;
            *(float4*)(outN + (size_t)n * OS + j0 + 4) = hi;
            if (b == 0) norms[n] = nrm;
        }
    }
}

extern "C" void kernel_launch(void* const* d_in, const int* in_sizes, int n_in,
                              void* d_out, int out_size, void* d_ws, size_t ws_size,
                              hipStream_t stream) {
    const int*   rows = (const int*)d_in[0];
    const int*   cols = (const int*)d_in[1];
    const float* vals = (const float*)d_in[2];
    const float* ue   = (const float*)d_in[3];
    const float* ie   = (const float*)d_in[4];
    const float* Wc   = (const float*)d_in[5];
    const float* bc   = (const float*)d_in[6];
    const float* We   = (const float*)d_in[7];
    const float* be   = (const float*)d_in[8];
    float* out = (float*)d_out;

    // ws layout: side first, then CSR arrays. cnt/cur overlap side (they are
    // only live during the CSR build; side only during layers).
    float* side   = (float*)d_ws;                 // NN*D floats (76.8 MB)
    int*   cnt    = (int*)side;                   // NN (build phase only)
    int*   cur    = cnt + NN;                     // NN (build phase only)
    int*   rowptr = (int*)(side + (size_t)NN * D);// NN+1
    int*   bsum   = rowptr + NN + 1;              // 512
    int*   cols_s = bsum + 512;                   // NNZE
    float* vals_s = (float*)(cols_s + NNZE);      // NNZE
    float* norms  = vals_s + NNZE;                // NN

    const int NB_SCAN = (NN + 1023) / 1024;  // 293

    // ---- build CSR ----
    hipMemsetAsync(cnt, 0, (size_t)NN * sizeof(int), stream);
    k_hist<<<(NNZE + 255) / 256, 256, 0, stream>>>(rows, cnt);
    k_scan1<<<NB_SCAN, 1024, 0, stream>>>(cnt, rowptr, bsum);
    k_scan2<<<1, 512, 0, stream>>>(bsum, NB_SCAN);
    k_scan3<<<NB_SCAN, 1024, 0, stream>>>(rowptr, bsum, cur);
    k_scatter<<<(NNZE + 255) / 256, 256, 0, stream>>>(rows, cols, vals, cur,
                                                      cols_s, vals_s);

    // ---- embeddings ----
    k_concat<<<(NN * 16 + 255) / 256, 256, 0, stream>>>(ue, ie, out);

    const int GB_SPMM = (NN * 16 + 255) / 256;
    const int GB_DENSE = (NN + 63) / 64;
    for (int l = 0; l < 3; l++) {
        if (l == 0) {
            k_spmm<false><<<GB_SPMM, 256, 0, stream>>>(
                rowptr, cols_s, vals_s, nullptr, out, side);
            k_dense<false><<<GB_DENSE, 256, 0, stream>>>(
                side, out, Wc, bc, We, be, out + 64, norms);
        } else {
            k_spmm<true><<<GB_SPMM, 256, 0, stream>>>(
                rowptr, cols_s, vals_s, norms, out + l * 64, side);
            k_dense<true><<<GB_DENSE, 256, 0, stream>>>(
                side, out + l * 64, Wc + l * 4096, bc + l * 64,
                We + l * 4096, be + l * 64, out + (l + 1) * 64, norms);
        }
    }
}

// Round 5
// 424.553 us; speedup vs baseline: 8.2753x; 1.6054x over previous
//
#include <hip/hip_runtime.h>

#define NU 100000
#define NI 200000
#define NN 300000
#define NNZE 1200000
#define D 64
#define OS 256   // (L+1)*D output row stride

typedef __attribute__((ext_vector_type(8))) short s16x8;
typedef __attribute__((ext_vector_type(4))) float f32x4;

__device__ __forceinline__ float bf2f(unsigned short u) {
    return __uint_as_float(((unsigned int)u) << 16);
}
__device__ __forceinline__ unsigned short f2bf(float f) {
    unsigned int u = __float_as_uint(f);
    u = (u + 0x7FFF + ((u >> 16) & 1)) >> 16;   // RNE
    return (unsigned short)u;
}

// ---------------- concat -> out chunk0 (fp32) + ebf (bf16 activation) --------
__global__ void k_concat(const float* __restrict__ ue, const float* __restrict__ ie,
                         float* __restrict__ out, unsigned short* __restrict__ ebf) {
    int idx = blockIdx.x * blockDim.x + threadIdx.x;
    if (idx >= NN * 16) return;
    int n = idx >> 4, c = idx & 15;
    float4 v;
    if (n < NU) v = ((const float4*)(ue + (size_t)n * D))[c];
    else        v = ((const float4*)(ie + (size_t)(n - NU) * D))[c];
    ((float4*)(out + (size_t)n * OS))[c] = v;
    ushort4 b;
    b.x = f2bf(v.x); b.y = f2bf(v.y); b.z = f2bf(v.z); b.w = f2bf(v.w);
    *(ushort4*)(ebf + (size_t)n * D + c * 4) = b;
}

// ---------------- CSR build ----------------
__global__ void k_hist(const int* __restrict__ rows, int* __restrict__ cnt) {
    int e = blockIdx.x * blockDim.x + threadIdx.x;
    if (e < NNZE) atomicAdd(&cnt[rows[e]], 1);
}

__global__ void k_scan1(const int* __restrict__ cnt, int* __restrict__ rowptr,
                        int* __restrict__ bsum) {
    __shared__ int s[1024];
    int t = threadIdx.x, g = blockIdx.x * 1024 + t;
    int x = (g < NN) ? cnt[g] : 0;
    s[t] = x;
    __syncthreads();
    for (int off = 1; off < 1024; off <<= 1) {
        int y = (t >= off) ? s[t - off] : 0;
        __syncthreads();
        s[t] += y;
        __syncthreads();
    }
    if (g < NN) rowptr[g + 1] = s[t];
    if (t == 1023) bsum[blockIdx.x] = s[1023];
}

__global__ void k_scan2(int* __restrict__ bsum, int nb) {
    __shared__ int s[512];
    int t = threadIdx.x;
    int x = (t < nb) ? bsum[t] : 0;
    s[t] = x;
    __syncthreads();
    for (int off = 1; off < 512; off <<= 1) {
        int y = (t >= off) ? s[t - off] : 0;
        __syncthreads();
        s[t] += y;
        __syncthreads();
    }
    if (t < nb) bsum[t] = s[t];
}

__global__ void k_scan3(int* __restrict__ rowptr, const int* __restrict__ bsum,
                        int* __restrict__ cur) {
    int t = threadIdx.x, g = blockIdx.x * 1024 + t;
    if (g < NN) {
        int off = (blockIdx.x > 0) ? bsum[blockIdx.x - 1] : 0;
        int v = rowptr[g + 1] + off;
        rowptr[g + 1] = v;
        if (g + 1 < NN) cur[g + 1] = v;
    }
    if (g == 0) { rowptr[0] = 0; cur[0] = 0; }
}

__global__ void k_scatter(const int* __restrict__ rows, const int* __restrict__ cols,
                          const float* __restrict__ vals, int* __restrict__ cur,
                          int* __restrict__ cols_s, float* __restrict__ vals_s) {
    int e = blockIdx.x * blockDim.x + threadIdx.x;
    if (e >= NNZE) return;
    int r = rows[e];
    int pos = atomicAdd(&cur[r], 1);
    cols_s[pos] = cols[e];
    vals_s[pos] = vals[e];
}

// ---------------- CSR SpMM (bf16 gather, fp32 accum, bf16 store) -------------
__global__ __launch_bounds__(256) void k_spmm(
    const int* __restrict__ rowptr, const int* __restrict__ cols_s,
    const float* __restrict__ vals_s,
    const unsigned short* __restrict__ ebf, unsigned short* __restrict__ sbf) {
    int t = blockIdx.x * blockDim.x + threadIdx.x;
    int g = t >> 4, lane = t & 15;
    if (g >= NN) return;
    int beg = rowptr[g], end = rowptr[g + 1];
    float a0 = 0.f, a1 = 0.f, a2 = 0.f, a3 = 0.f;
    int i = beg;
    for (; i + 1 < end; i += 2) {
        int c0 = cols_s[i], c1 = cols_s[i + 1];
        float v0 = vals_s[i], v1 = vals_s[i + 1];
        ushort4 g0 = *(const ushort4*)(ebf + (size_t)c0 * D + lane * 4);
        ushort4 g1 = *(const ushort4*)(ebf + (size_t)c1 * D + lane * 4);
        a0 += v0 * bf2f(g0.x) + v1 * bf2f(g1.x);
        a1 += v0 * bf2f(g0.y) + v1 * bf2f(g1.y);
        a2 += v0 * bf2f(g0.z) + v1 * bf2f(g1.z);
        a3 += v0 * bf2f(g0.w) + v1 * bf2f(g1.w);
    }
    if (i < end) {
        int c0 = cols_s[i];
        float v0 = vals_s[i];
        ushort4 g0 = *(const ushort4*)(ebf + (size_t)c0 * D + lane * 4);
        a0 += v0 * bf2f(g0.x); a1 += v0 * bf2f(g0.y);
        a2 += v0 * bf2f(g0.z); a3 += v0 * bf2f(g0.w);
    }
    ushort4 r;
    r.x = f2bf(a0); r.y = f2bf(a1); r.z = f2bf(a2); r.w = f2bf(a3);
    *(ushort4*)(sbf + (size_t)g * D + lane * 4) = r;
}

// ---------------- MFMA dense + leakyrelu + normalize + ebf update ------------
// Block: 64 nodes, 256 threads = 4 waves; wave w owns rows [16w,16w+16).
// out = leakyrelu(sbf@Wc + bc + (sbf.*ebf)@We + be); outN gets normalized fp32,
// ebf gets unnormalized bf16 (in-place, wave-local rows only).
__global__ __launch_bounds__(256) void k_dense(
    const unsigned short* __restrict__ sbf, unsigned short* __restrict__ ebf,
    const float* __restrict__ Wc, const float* __restrict__ bc,
    const float* __restrict__ We, const float* __restrict__ be,
    float* __restrict__ outN) {
    __shared__ unsigned short sWT[2][64 * 64];  // W transposed [n][k] bf16, XOR-swizzled

    int tid = threadIdx.x;
    int n0 = blockIdx.x * 64;

    // stage both W matrices transposed->bf16 into LDS (once per block)
    #pragma unroll
    for (int m = 0; m < 2; m++) {
        const float* W = m ? We : Wc;
        int base = tid * 16;            // 4096 elements / 256 threads
        int k = base >> 6, n = base & 63;
        #pragma unroll
        for (int i = 0; i < 4; i++) {
            float4 v = *(const float4*)(W + k * 64 + n + i * 4);
            #pragma unroll
            for (int j = 0; j < 4; j++) {
                int col = n + i * 4 + j;
                int byteoff = (col * 128 + k * 2) ^ ((col & 7) << 4);
                float fv = (j == 0) ? v.x : (j == 1) ? v.y : (j == 2) ? v.z : v.w;
                *(unsigned short*)((char*)&sWT[m][0] + byteoff) = f2bf(fv);
            }
        }
    }

    int wid = tid >> 6, lane = tid & 63;
    int lg = lane >> 4, lr = lane & 15;

    // A-fragments straight from global bf16 (each row read by exactly one wave)
    int rowA = n0 + wid * 16 + lr;
    int rowAc = rowA < NN ? rowA : NN - 1;
    size_t abase = (size_t)rowAc * D;
    s16x8 sf[2], ef[2], wf[2];
    sf[0] = *(const s16x8*)(sbf + abase + lg * 8);
    sf[1] = *(const s16x8*)(sbf + abase + 32 + lg * 8);
    ef[0] = *(const s16x8*)(ebf + abase + lg * 8);
    ef[1] = *(const s16x8*)(ebf + abase + 32 + lg * 8);
    #pragma unroll
    for (int kb = 0; kb < 2; kb++) {
        #pragma unroll
        for (int j = 0; j < 8; j++) {
            float p = bf2f((unsigned short)sf[kb][j]) * bf2f((unsigned short)ef[kb][j]);
            wf[kb][j] = (short)f2bf(p);
        }
    }

    f32x4 acc[4];
    #pragma unroll
    for (int c = 0; c < 4; c++) {
        float bj = bc[c * 16 + lr] + be[c * 16 + lr];
        acc[c] = (f32x4){bj, bj, bj, bj};
    }

    __syncthreads();

    #pragma unroll
    for (int c = 0; c < 4; c++) {
        #pragma unroll
        for (int kb = 0; kb < 2; kb++) {
            int row = c * 16 + lr;
            int byteoff = (row * 128 + (kb * 32 + lg * 8) * 2) ^ ((row & 7) << 4);
            s16x8 bWc = *(const s16x8*)((const char*)&sWT[0][0] + byteoff);
            s16x8 bWe = *(const s16x8*)((const char*)&sWT[1][0] + byteoff);
            acc[c] = __builtin_amdgcn_mfma_f32_16x16x32_bf16(sf[kb], bWc, acc[c], 0, 0, 0);
            acc[c] = __builtin_amdgcn_mfma_f32_16x16x32_bf16(wf[kb], bWe, acc[c], 0, 0, 0);
        }
    }

    // leaky-relu + row ssq; D layout: col = c*16+lr, row = n0+wid*16+lg*4+r
    float o[4][4];
    float ssq[4] = {0.f, 0.f, 0.f, 0.f};
    #pragma unroll
    for (int c = 0; c < 4; c++) {
        #pragma unroll
        for (int r = 0; r < 4; r++) {
            float x = acc[c][r];
            float y = (x > 0.f) ? x : 0.2f * x;
            o[c][r] = y;
            ssq[r] += y * y;
        }
    }
    #pragma unroll
    for (int r = 0; r < 4; r++) {
        ssq[r] += __shfl_xor(ssq[r], 1);
        ssq[r] += __shfl_xor(ssq[r], 2);
        ssq[r] += __shfl_xor(ssq[r], 4);
        ssq[r] += __shfl_xor(ssq[r], 8);
    }
    #pragma unroll
    for (int r = 0; r < 4; r++) {
        int row = n0 + wid * 16 + lg * 4 + r;
        if (row < NN) {
            float sc = 1.0f / fmaxf(sqrtf(ssq[r]), 1e-12f);
            #pragma unroll
            for (int c = 0; c < 4; c++) {
                outN[(size_t)row * OS + c * 16 + lr] = o[c][r] * sc;
                ebf[(size_t)row * D + c * 16 + lr] = f2bf(o[c][r]);
            }
        }
    }
}

extern "C" void kernel_launch(void* const* d_in, const int* in_sizes, int n_in,
                              void* d_out, int out_size, void* d_ws, size_t ws_size,
                              hipStream_t stream) {
    const int*   rows = (const int*)d_in[0];
    const int*   cols = (const int*)d_in[1];
    const float* vals = (const float*)d_in[2];
    const float* ue   = (const float*)d_in[3];
    const float* ie   = (const float*)d_in[4];
    const float* Wc   = (const float*)d_in[5];
    const float* bc   = (const float*)d_in[6];
    const float* We   = (const float*)d_in[7];
    const float* be   = (const float*)d_in[8];
    float* out = (float*)d_out;

    // ws layout (~88 MB): ebf, sbf (bf16), then CSR. cnt/cur (build-only)
    // overlap ebf (concat runs after scatter).
    unsigned short* ebf = (unsigned short*)d_ws;            // NN*D bf16 (38.4MB)
    unsigned short* sbf = ebf + (size_t)NN * D;             // NN*D bf16 (38.4MB)
    int*   cnt    = (int*)d_ws;                             // NN (build only)
    int*   cur    = cnt + NN;                               // NN (build only)
    int*   rowptr = (int*)(sbf + (size_t)NN * D);           // NN+1
    int*   bsum   = rowptr + NN + 1;                        // 512
    int*   cols_s = bsum + 512;                             // NNZE
    float* vals_s = (float*)(cols_s + NNZE);                // NNZE

    const int NB_SCAN = (NN + 1023) / 1024;  // 293

    // ---- build CSR ----
    hipMemsetAsync(cnt, 0, (size_t)NN * sizeof(int), stream);
    k_hist<<<(NNZE + 255) / 256, 256, 0, stream>>>(rows, cnt);
    k_scan1<<<NB_SCAN, 1024, 0, stream>>>(cnt, rowptr, bsum);
    k_scan2<<<1, 512, 0, stream>>>(bsum, NB_SCAN);
    k_scan3<<<NB_SCAN, 1024, 0, stream>>>(rowptr, bsum, cur);
    k_scatter<<<(NNZE + 255) / 256, 256, 0, stream>>>(rows, cols, vals, cur,
                                                      cols_s, vals_s);

    // ---- embeddings (also initializes ebf; must follow scatter) ----
    k_concat<<<(NN * 16 + 255) / 256, 256, 0, stream>>>(ue, ie, out, ebf);

    const int GB_SPMM = (NN * 16 + 255) / 256;
    const int GB_DENSE = (NN + 63) / 64;
    for (int l = 0; l < 3; l++) {
        k_spmm<<<GB_SPMM, 256, 0, stream>>>(rowptr, cols_s, vals_s, ebf, sbf);
        k_dense<<<GB_DENSE, 256, 0, stream>>>(
            sbf, ebf, Wc + l * 4096, bc + l * 64,
            We + l * 4096, be + l * 64, out + (l + 1) * 64);
    }
}